// Round 2
// baseline (3492.751 us; speedup 1.0000x reference)
//
#include <hip/hip_runtime.h>
#include <cstdint>

#define NPIX 16384
#define KNN 8

// ---------------- Threefry-2x32 (exact JAX semantics: 20 rounds) ----------------
__host__ __device__ __forceinline__ void tf2x32(uint32_t k0, uint32_t k1,
                                                uint32_t x0, uint32_t x1,
                                                uint32_t& o0, uint32_t& o1) {
  uint32_t ks2 = k0 ^ k1 ^ 0x1BD11BDAu;
  x0 += k0; x1 += k1;
#define TFR(r) { x0 += x1; x1 = (x1 << r) | (x1 >> (32 - r)); x1 ^= x0; }
  TFR(13) TFR(15) TFR(26) TFR(6)  x0 += k1;  x1 += ks2 + 1u;
  TFR(17) TFR(29) TFR(16) TFR(24) x0 += ks2; x1 += k0 + 2u;
  TFR(13) TFR(15) TFR(26) TFR(6)  x0 += k0;  x1 += k1 + 3u;
  TFR(17) TFR(29) TFR(16) TFR(24) x0 += k1;  x1 += ks2 + 4u;
  TFR(13) TFR(15) TFR(26) TFR(6)  x0 += ks2; x1 += k0 + 5u;
#undef TFR
  o0 = x0; o1 = x1;
}

// partitionable-threefry random_bits (32-bit): element j -> w0^w1 of TF(key,(0,j))
__device__ __forceinline__ uint32_t rbits32(uint32_t ka, uint32_t kb, uint32_t j) {
  uint32_t o0, o1;
  tf2x32(ka, kb, 0u, j, o0, o1);
  return o0 ^ o1;
}

// randint element draw under partitionable threefry.
// K = (k1a,k1b,k2a,k2b) where k1,k2 = foldlike-split(randint key).
__device__ __forceinline__ int rnd_int(uint4 K, uint32_t j, uint32_t span,
                                       uint32_t mult, int minv) {
  uint32_t hi = rbits32(K.x, K.y, j);
  uint32_t lo = rbits32(K.z, K.w, j);
  uint32_t off = ((hi % span) * mult + (lo % span)) % span;
  return minv + (int)off;
}

// ---------------- patch SSD cost -------------------------------------------------
// Bit-exact replica of XLA-CPU's f32 column reduction: sequential accumulation in
// (c, d) lexicographic order (d = dy*3+dx), plain mul+add (no FMA contraction).
__device__ float cost_eval(const float* __restrict__ a, const float* __restrict__ b,
                           int h, int w, int sy, int sx) {
  int ay[3], ax[3], by[3], bx[3];
#pragma unroll
  for (int d = 0; d < 3; ++d) {
    int t;
    t = h + d - 1;  ay[d] = t < 0 ? 0 : (t > 127 ? 127 : t);
    t = w + d - 1;  ax[d] = t < 0 ? 0 : (t > 127 ? 127 : t);
    t = sy + d - 1; by[d] = t < 0 ? 0 : (t > 127 ? 127 : t);
    t = sx + d - 1; bx[d] = t < 0 ? 0 : (t > 127 ? 127 : t);
  }
  float acc = 0.f;
  for (int c = 0; c < 32; ++c) {
    const float* ac = a + (c << 14);
    const float* bc = b + (c << 14);
#pragma unroll
    for (int dy = 0; dy < 3; ++dy) {
      const float* ar = ac + (ay[dy] << 7);
      const float* br = bc + (by[dy] << 7);
#pragma unroll
      for (int dx = 0; dx < 3; ++dx) {
        float d = __fsub_rn(ar[ax[dx]], br[bx[dx]]);
        acc = __fadd_rn(acc, __fmul_rn(d, d));
      }
    }
  }
  return acc;
}

// ---------------- init: random shifts + their costs -----------------------------
__global__ __launch_bounds__(256) void init_kernel(
    const float* __restrict__ a, const float* __restrict__ b,
    uint32_t* __restrict__ npack, float* __restrict__ ncost, uint4 IK) {
  int wid = (int)((blockIdx.x * blockDim.x + threadIdx.x) >> 6);
  int lane = (int)(threadIdx.x & 63u);
  int pix = wid;
  int h = pix >> 7, w = pix & 127;
  if (lane >= 8) return;
  int s = lane;
  uint32_t j0 = (uint32_t)(s * 2) * 16384u + (uint32_t)pix;
  int sy = rnd_int(IK, j0, 128u, 0u, 0);
  int sx = rnd_int(IK, j0 + 16384u, 128u, 0u, 0);
  float cst = cost_eval(a, b, h, w, sy, sx);
  npack[s * NPIX + pix] = (uint32_t)((sy << 7) | sx);
  ncost[s * NPIX + pix] = cst;
}

// ---------------- one PatchMatch iteration (wave per pixel) ---------------------
__global__ __launch_bounds__(256) void step_kernel(
    const float* __restrict__ a, const float* __restrict__ b,
    const uint32_t* __restrict__ ppack, const float* __restrict__ pcost,
    uint32_t* __restrict__ npack, float* __restrict__ ncost,
    uint4 K0, uint4 K1, uint4 K2, uint4 K3) {
  int wid = (int)((blockIdx.x * blockDim.x + threadIdx.x) >> 6);
  int lane = (int)(threadIdx.x & 63u);
  int pix = wid;
  int h = pix >> 7, w = pix & 127;
  int g = lane >> 3, s = lane & 7;

  uint32_t old_pack = 0u; float old_cost_f = 0.f;
  if (lane < 8) {
    old_pack = ppack[lane * NPIX + pix];
    old_cost_f = pcost[lane * NPIX + pix];
  }

  // candidate generation; order matches all_s = [old8, left8, right8, up8, down8, r0..r3]
  int sy, sx;
  if (g < 4) {
    int nh = h, nw = w, dsy = 0, dsx = 0;
    if (g == 0)      { nw = (w + 127) & 127; dsx = 1;  }
    else if (g == 1) { nw = (w + 1) & 127;   dsx = -1; }
    else if (g == 2) { nh = (h + 127) & 127; dsy = 1;  }
    else             { nh = (h + 1) & 127;   dsy = -1; }
    uint32_t p = ppack[s * NPIX + (nh << 7) + nw];
    sy = (int)(p >> 7) + dsy;
    sx = (int)(p & 127u) + dsx;
  } else {
    uint32_t p = ppack[s * NPIX + pix];
    uint4 Ki      = (g == 4) ? K0   : (g == 5) ? K1  : (g == 6) ? K2 : K3;
    uint32_t span = (g == 4) ? 129u : (g == 5) ? 33u : (g == 6) ? 9u : 3u;
    uint32_t mult = (g == 4) ? 16u  : (g == 5) ? 4u  : (g == 6) ? 4u : 1u;
    int minv      = (g == 4) ? -64  : (g == 5) ? -16 : (g == 6) ? -4 : -1;
    uint32_t j0 = (uint32_t)(s * 2) * 16384u + (uint32_t)pix;
    sy = (int)(p >> 7)   + rnd_int(Ki, j0, span, mult, minv);
    sx = (int)(p & 127u) + rnd_int(Ki, j0 + 16384u, span, mult, minv);
  }
  sy = sy < 0 ? 0 : (sy > 127 ? 127 : sy);
  sx = sx < 0 ? 0 : (sx > 127 ? 127 : sx);

  float cnd_cost = cost_eval(a, b, h, w, sy, sx);
  uint32_t cnd_pack = (uint32_t)((sy << 7) | sx);

  // stable top-8 (ascending cost, ties -> lower candidate idx), matching lax.top_k
  unsigned long long new_key =
      ((unsigned long long)__float_as_uint(cnd_cost) << 32) | (unsigned)(8 + lane);
  unsigned long long old_key = (lane < 8)
      ? (((unsigned long long)__float_as_uint(old_cost_f) << 32) | (unsigned)lane)
      : ~0ull;
  bool new_used = false, old_used = (lane >= 8);

  unsigned long long wk0, wk1, wk2, wk3, wk4, wk5, wk6, wk7;
#define SELECT_ROUND(WK)                                                   \
  {                                                                        \
    unsigned long long kmin = new_used ? ~0ull : new_key;                  \
    if (!old_used && old_key < kmin) kmin = old_key;                       \
    _Pragma("unroll")                                                      \
    for (int off = 32; off; off >>= 1) {                                   \
      unsigned long long o = __shfl_xor(kmin, off);                        \
      if (o < kmin) kmin = o;                                              \
    }                                                                      \
    WK = kmin;                                                             \
    if (!new_used && new_key == kmin) new_used = true;                     \
    else if (!old_used && old_key == kmin) old_used = true;                \
  }
  SELECT_ROUND(wk0) SELECT_ROUND(wk1) SELECT_ROUND(wk2) SELECT_ROUND(wk3)
  SELECT_ROUND(wk4) SELECT_ROUND(wk5) SELECT_ROUND(wk6) SELECT_ROUND(wk7)
#undef SELECT_ROUND

  uint32_t out_pack = 0u; float out_cost = 0.f;
#define EXTRACT_ROUND(R, WK)                                               \
  {                                                                        \
    unsigned long long kmin = WK;                                          \
    uint32_t idx = (uint32_t)kmin;                                         \
    float cst = __uint_as_float((uint32_t)(kmin >> 32));                   \
    int srcOld = (idx < 8u) ? (int)idx : 0;                                \
    int srcNew = (idx >= 8u) ? (int)(idx - 8u) : 0;                        \
    uint32_t po = __shfl(old_pack, srcOld);                                \
    uint32_t pn = __shfl(cnd_pack, srcNew);                                \
    uint32_t pk = (idx < 8u) ? po : pn;                                    \
    if (lane == R) { out_pack = pk; out_cost = cst; }                      \
  }
  EXTRACT_ROUND(0, wk0) EXTRACT_ROUND(1, wk1) EXTRACT_ROUND(2, wk2)
  EXTRACT_ROUND(3, wk3) EXTRACT_ROUND(4, wk4) EXTRACT_ROUND(5, wk5)
  EXTRACT_ROUND(6, wk6) EXTRACT_ROUND(7, wk7)
#undef EXTRACT_ROUND

  if (lane < 8) {
    npack[lane * NPIX + pix] = out_pack;
    ncost[lane * NPIX + pix] = out_cost;
  }
}

// ---------------- softmax weights over 8 costs ----------------------------------
__global__ __launch_bounds__(256) void weights_kernel(
    const float* __restrict__ cost0, float* __restrict__ wbuf) {
  int pix = (int)(blockIdx.x * blockDim.x + threadIdx.x);
  if (pix >= NPIX) return;
  float c[KNN];
  float m = 3.4e38f;
#pragma unroll
  for (int s = 0; s < KNN; ++s) { c[s] = cost0[s * NPIX + pix]; m = fminf(m, c[s]); }
  float e[KNN]; float sum = 0.f;
#pragma unroll
  for (int s = 0; s < KNN; ++s) { e[s] = expf(m - c[s]); sum += e[s]; }
  float inv = 1.f / sum;
#pragma unroll
  for (int s = 0; s < KNN; ++s) wbuf[s * NPIX + pix] = e[s] * inv;
}

// ---------------- weighted gather of v ------------------------------------------
__global__ __launch_bounds__(256) void out_kernel(
    const float* __restrict__ v, const uint32_t* __restrict__ pack0,
    const float* __restrict__ wbuf, float* __restrict__ out) {
  int t = (int)(blockIdx.x * blockDim.x + threadIdx.x);  // 4*64*128*128 threads
  int pix = t & (NPIX - 1);
  int ch = t >> 14;  // n*64 + c2
  const float* vc = v + ((size_t)ch << 14);
  float acc = 0.f;
#pragma unroll
  for (int s = 0; s < KNN; ++s) {
    uint32_t p = pack0[s * NPIX + pix];   // p == sy*128+sx
    float wgt = wbuf[s * NPIX + pix];
    acc = fmaf(wgt, vc[p], acc);
  }
  out[t] = acc;
}

// ---------------- host helpers ---------------------------------------------------
// foldlike split (jax_threefry_partitionable=True): key_i = TF(key, (0, i))
static void h_split_fl(uint32_t ka, uint32_t kb, uint32_t o[4]) {
  tf2x32(ka, kb, 0u, 0u, o[0], o[1]);  // keys[0]
  tf2x32(ka, kb, 0u, 1u, o[2], o[3]);  // keys[1]
}

extern "C" void kernel_launch(void* const* d_in, const int* in_sizes, int n_in,
                              void* d_out, int out_size, void* d_ws, size_t ws_size,
                              hipStream_t stream) {
  const float* q = (const float*)d_in[0];  // (1,32,128,128)
  const float* k = (const float*)d_in[1];  // (1,32,128,128)
  const float* v = (const float*)d_in[2];  // (4,64,128,128)
  float* out = (float*)d_out;

  uint32_t* ws = (uint32_t*)d_ws;
  uint32_t* pk[2] = { ws, ws + (size_t)KNN * NPIX };
  float* ct[2] = { (float*)(ws + (size_t)2 * KNN * NPIX),
                   (float*)(ws + (size_t)3 * KNN * NPIX) };
  float* wbuf = (float*)(ws + (size_t)4 * KNN * NPIX);

  // key chain on host (pure arithmetic; graph-capture safe, deterministic)
  uint32_t sp[4];
  h_split_fl(0u, 42u, sp);                      // split(key(42)) [foldlike]
  uint32_t k0a = sp[0], k0b = sp[1];            // k0  (initial randint key)
  uint32_t kMa = sp[2], kMb = sp[3];            // key (closed over by scan body)

  uint32_t ik[4];
  h_split_fl(k0a, k0b, ik);                     // randint's internal split of k0
  init_kernel<<<4096, 256, 0, stream>>>(q, k, pk[0], ct[0],
                                        make_uint4(ik[0], ik[1], ik[2], ik[3]));

  for (int it = 0; it < 10; ++it) {
    uint32_t ka, kb;
    tf2x32(kMa, kMb, 0u, (uint32_t)it, ka, kb); // kk = fold_in(key, it)
    uint4 K[4];
    for (int i = 0; i < 4; ++i) {
      uint32_t ia, ib;
      tf2x32(ka, kb, 0u, (uint32_t)i, ia, ib);  // ki = fold_in(kk, i)
      uint32_t o[4];
      h_split_fl(ia, ib, o);                    // randint's internal split of ki
      K[i] = make_uint4(o[0], o[1], o[2], o[3]);
    }
    step_kernel<<<4096, 256, 0, stream>>>(q, k, pk[it & 1], ct[it & 1],
                                          pk[(it + 1) & 1], ct[(it + 1) & 1],
                                          K[0], K[1], K[2], K[3]);
  }

  weights_kernel<<<NPIX / 256, 256, 0, stream>>>(ct[0], wbuf);
  out_kernel<<<(4 * 64 * NPIX) / 256, 256, 0, stream>>>(v, pk[0], wbuf, out);
}

// Round 3
// 1923.789 us; speedup vs baseline: 1.8156x; 1.8156x over previous
//
#include <hip/hip_runtime.h>
#include <cstdint>

#define NPIX 16384
#define KNN 8
#define PW 130           // padded width/height
#define PCH (PW * PW)    // 16900 floats per padded channel

// ---------------- Threefry-2x32 (exact JAX semantics: 20 rounds) ----------------
__host__ __device__ __forceinline__ void tf2x32(uint32_t k0, uint32_t k1,
                                                uint32_t x0, uint32_t x1,
                                                uint32_t& o0, uint32_t& o1) {
  uint32_t ks2 = k0 ^ k1 ^ 0x1BD11BDAu;
  x0 += k0; x1 += k1;
#define TFR(r) { x0 += x1; x1 = (x1 << r) | (x1 >> (32 - r)); x1 ^= x0; }
  TFR(13) TFR(15) TFR(26) TFR(6)  x0 += k1;  x1 += ks2 + 1u;
  TFR(17) TFR(29) TFR(16) TFR(24) x0 += ks2; x1 += k0 + 2u;
  TFR(13) TFR(15) TFR(26) TFR(6)  x0 += k0;  x1 += k1 + 3u;
  TFR(17) TFR(29) TFR(16) TFR(24) x0 += k1;  x1 += ks2 + 4u;
  TFR(13) TFR(15) TFR(26) TFR(6)  x0 += ks2; x1 += k0 + 5u;
#undef TFR
  o0 = x0; o1 = x1;
}

// partitionable-threefry random_bits (32-bit): element j -> w0^w1 of TF(key,(0,j))
__device__ __forceinline__ uint32_t rbits32(uint32_t ka, uint32_t kb, uint32_t j) {
  uint32_t o0, o1;
  tf2x32(ka, kb, 0u, j, o0, o1);
  return o0 ^ o1;
}

// randint element draw; K = (k1a,k1b,k2a,k2b) = foldlike-split of randint key
__device__ __forceinline__ int rnd_int(uint4 K, uint32_t j, uint32_t span,
                                       uint32_t mult, int minv) {
  uint32_t hi = rbits32(K.x, K.y, j);
  uint32_t lo = rbits32(K.z, K.w, j);
  uint32_t off = ((hi % span) * mult + (lo % span)) % span;
  return minv + (int)off;
}

// 12-byte row load (alignment 4, never OOB past the 3 used floats)
__device__ __forceinline__ void ld3(const float* __restrict__ p,
                                    float& x, float& y, float& z) {
  float t[3];
  __builtin_memcpy(t, p, 12);
  x = t[0]; y = t[1]; z = t[2];
}

// ---------------- patch SSD cost on padded images -------------------------------
// Bit-exact (c, dy, dx) sequential f32 accumulation, no FMA contraction.
__device__ __forceinline__ float cost_eval(const float* __restrict__ ap,
                                           const float* __restrict__ bp,
                                           int pa, int pb) {
  const float* ar = ap + pa;
  const float* br = bp + pb;
  float acc = 0.f;
#pragma unroll 2
  for (int c = 0; c < 32; ++c) {
#pragma unroll
    for (int dy = 0; dy < 3; ++dy) {
      float a0, a1, a2, b0, b1, b2;
      ld3(ar + dy * PW, a0, a1, a2);
      ld3(br + dy * PW, b0, b1, b2);
      float d0 = __fsub_rn(a0, b0); acc = __fadd_rn(acc, __fmul_rn(d0, d0));
      float d1 = __fsub_rn(a1, b1); acc = __fadd_rn(acc, __fmul_rn(d1, d1));
      float d2 = __fsub_rn(a2, b2); acc = __fadd_rn(acc, __fmul_rn(d2, d2));
    }
    ar += PCH; br += PCH;
  }
  return acc;
}

// ---------------- pad a,b to 130x130 with edge clamp ----------------------------
__global__ __launch_bounds__(256) void pad_kernel(
    const float* __restrict__ a, const float* __restrict__ b,
    float* __restrict__ ap, float* __restrict__ bp) {
  int t = (int)(blockIdx.x * blockDim.x + threadIdx.x);
  if (t >= 32 * PCH) return;
  int c = t / PCH, r = t % PCH;
  int py = r / PW, px = r % PW;
  int y = py - 1; y = y < 0 ? 0 : (y > 127 ? 127 : y);
  int x = px - 1; x = x < 0 ? 0 : (x > 127 ? 127 : x);
  int src = (c << 14) + (y << 7) + x;
  ap[t] = a[src];
  bp[t] = b[src];
}

// ---------------- init: random shifts + their costs (full-wave) -----------------
__global__ __launch_bounds__(256) void init_kernel(
    const float* __restrict__ ap, const float* __restrict__ bp,
    uint32_t* __restrict__ npack, float* __restrict__ ncost, uint4 IK) {
  int t = (int)(blockIdx.x * blockDim.x + threadIdx.x);  // 8*16384
  int pix = t & (NPIX - 1);
  int s = t >> 14;
  int h = pix >> 7, w = pix & 127;
  uint32_t j0 = (uint32_t)(s * 2) * 16384u + (uint32_t)pix;
  int sy = rnd_int(IK, j0, 128u, 0u, 0);
  int sx = rnd_int(IK, j0 + 16384u, 128u, 0u, 0);
  float cst = cost_eval(ap, bp, h * PW + w, sy * PW + sx);
  npack[t] = (uint32_t)((sy << 7) | sx);
  ncost[t] = cst;
}

// ---------------- one PatchMatch iteration (wave per pixel) ---------------------
__global__ __launch_bounds__(256) void step_kernel(
    const float* __restrict__ ap, const float* __restrict__ bp,
    const uint32_t* __restrict__ ppack, const float* __restrict__ pcost,
    uint32_t* __restrict__ npack, float* __restrict__ ncost,
    uint4 K0, uint4 K1, uint4 K2, uint4 K3) {
  int wid = (int)((blockIdx.x * blockDim.x + threadIdx.x) >> 6);
  int lane = (int)(threadIdx.x & 63u);
  int pix = wid;
  int h = pix >> 7, w = pix & 127;
  int g = lane >> 3, s = lane & 7;

  uint32_t old_pack = 0u; float old_cost_f = 0.f;
  if (lane < 8) {
    old_pack = ppack[lane * NPIX + pix];
    old_cost_f = pcost[lane * NPIX + pix];
  }

  // candidate generation; order matches all_s = [old8, left8, right8, up8, down8, r0..r3]
  int sy, sx;
  if (g < 4) {
    int nh = h, nw = w, dsy = 0, dsx = 0;
    if (g == 0)      { nw = (w + 127) & 127; dsx = 1;  }
    else if (g == 1) { nw = (w + 1) & 127;   dsx = -1; }
    else if (g == 2) { nh = (h + 127) & 127; dsy = 1;  }
    else             { nh = (h + 1) & 127;   dsy = -1; }
    uint32_t p = ppack[s * NPIX + (nh << 7) + nw];
    sy = (int)(p >> 7) + dsy;
    sx = (int)(p & 127u) + dsx;
  } else {
    uint32_t p = ppack[s * NPIX + pix];
    uint4 Ki      = (g == 4) ? K0   : (g == 5) ? K1  : (g == 6) ? K2 : K3;
    uint32_t span = (g == 4) ? 129u : (g == 5) ? 33u : (g == 6) ? 9u : 3u;
    uint32_t mult = (g == 4) ? 16u  : (g == 5) ? 4u  : (g == 6) ? 4u : 1u;
    int minv      = (g == 4) ? -64  : (g == 5) ? -16 : (g == 6) ? -4 : -1;
    uint32_t j0 = (uint32_t)(s * 2) * 16384u + (uint32_t)pix;
    sy = (int)(p >> 7)   + rnd_int(Ki, j0, span, mult, minv);
    sx = (int)(p & 127u) + rnd_int(Ki, j0 + 16384u, span, mult, minv);
  }
  sy = sy < 0 ? 0 : (sy > 127 ? 127 : sy);
  sx = sx < 0 ? 0 : (sx > 127 ? 127 : sx);
  uint32_t cnd_pack = (uint32_t)((sy << 7) | sx);

  // dedup: candidate equal to a carried shift has the identical (bit-exact) cost
  bool dup = false; float dup_cost = 0.f;
#pragma unroll
  for (int i = 0; i < 8; ++i) {
    uint32_t op = __shfl(old_pack, i);
    float oc = __shfl(old_cost_f, i);
    bool m = (op == cnd_pack);
    dup = dup || m;
    dup_cost = m ? oc : dup_cost;
  }

  float cnd_cost;
  if (dup) cnd_cost = dup_cost;
  else     cnd_cost = cost_eval(ap, bp, h * PW + w, sy * PW + sx);

  // stable top-8 (ascending cost, ties -> lower candidate idx), matching lax.top_k
  unsigned long long new_key =
      ((unsigned long long)__float_as_uint(cnd_cost) << 32) | (unsigned)(8 + lane);
  unsigned long long old_key = (lane < 8)
      ? (((unsigned long long)__float_as_uint(old_cost_f) << 32) | (unsigned)lane)
      : ~0ull;
  bool new_used = false, old_used = (lane >= 8);

  unsigned long long wk0, wk1, wk2, wk3, wk4, wk5, wk6, wk7;
#define SELECT_ROUND(WK)                                                   \
  {                                                                        \
    unsigned long long kmin = new_used ? ~0ull : new_key;                  \
    if (!old_used && old_key < kmin) kmin = old_key;                       \
    _Pragma("unroll")                                                      \
    for (int off = 32; off; off >>= 1) {                                   \
      unsigned long long o = __shfl_xor(kmin, off);                        \
      if (o < kmin) kmin = o;                                              \
    }                                                                      \
    WK = kmin;                                                             \
    if (!new_used && new_key == kmin) new_used = true;                     \
    else if (!old_used && old_key == kmin) old_used = true;                \
  }
  SELECT_ROUND(wk0) SELECT_ROUND(wk1) SELECT_ROUND(wk2) SELECT_ROUND(wk3)
  SELECT_ROUND(wk4) SELECT_ROUND(wk5) SELECT_ROUND(wk6) SELECT_ROUND(wk7)
#undef SELECT_ROUND

  uint32_t out_pack = 0u; float out_cost = 0.f;
#define EXTRACT_ROUND(R, WK)                                               \
  {                                                                        \
    unsigned long long kmin = WK;                                          \
    uint32_t idx = (uint32_t)kmin;                                         \
    float cst = __uint_as_float((uint32_t)(kmin >> 32));                   \
    int srcOld = (idx < 8u) ? (int)idx : 0;                                \
    int srcNew = (idx >= 8u) ? (int)(idx - 8u) : 0;                        \
    uint32_t po = __shfl(old_pack, srcOld);                                \
    uint32_t pn = __shfl(cnd_pack, srcNew);                                \
    uint32_t pk = (idx < 8u) ? po : pn;                                    \
    if (lane == R) { out_pack = pk; out_cost = cst; }                      \
  }
  EXTRACT_ROUND(0, wk0) EXTRACT_ROUND(1, wk1) EXTRACT_ROUND(2, wk2)
  EXTRACT_ROUND(3, wk3) EXTRACT_ROUND(4, wk4) EXTRACT_ROUND(5, wk5)
  EXTRACT_ROUND(6, wk6) EXTRACT_ROUND(7, wk7)
#undef EXTRACT_ROUND

  if (lane < 8) {
    npack[lane * NPIX + pix] = out_pack;
    ncost[lane * NPIX + pix] = out_cost;
  }
}

// ---------------- softmax weights over 8 costs ----------------------------------
__global__ __launch_bounds__(256) void weights_kernel(
    const float* __restrict__ cost0, float* __restrict__ wbuf) {
  int pix = (int)(blockIdx.x * blockDim.x + threadIdx.x);
  if (pix >= NPIX) return;
  float c[KNN];
  float m = 3.4e38f;
#pragma unroll
  for (int s = 0; s < KNN; ++s) { c[s] = cost0[s * NPIX + pix]; m = fminf(m, c[s]); }
  float e[KNN]; float sum = 0.f;
#pragma unroll
  for (int s = 0; s < KNN; ++s) { e[s] = expf(m - c[s]); sum += e[s]; }
  float inv = 1.f / sum;
#pragma unroll
  for (int s = 0; s < KNN; ++s) wbuf[s * NPIX + pix] = e[s] * inv;
}

// ---------------- weighted gather of v ------------------------------------------
__global__ __launch_bounds__(256) void out_kernel(
    const float* __restrict__ v, const uint32_t* __restrict__ pack0,
    const float* __restrict__ wbuf, float* __restrict__ out) {
  int t = (int)(blockIdx.x * blockDim.x + threadIdx.x);  // 4*64*128*128 threads
  int pix = t & (NPIX - 1);
  int ch = t >> 14;  // n*64 + c2
  const float* vc = v + ((size_t)ch << 14);
  float acc = 0.f;
#pragma unroll
  for (int s = 0; s < KNN; ++s) {
    uint32_t p = pack0[s * NPIX + pix];   // p == sy*128+sx
    float wgt = wbuf[s * NPIX + pix];
    acc = fmaf(wgt, vc[p], acc);
  }
  out[t] = acc;
}

// ---------------- host helpers ---------------------------------------------------
// foldlike split (jax_threefry_partitionable=True): key_i = TF(key, (0, i))
static void h_split_fl(uint32_t ka, uint32_t kb, uint32_t o[4]) {
  tf2x32(ka, kb, 0u, 0u, o[0], o[1]);  // keys[0]
  tf2x32(ka, kb, 0u, 1u, o[2], o[3]);  // keys[1]
}

extern "C" void kernel_launch(void* const* d_in, const int* in_sizes, int n_in,
                              void* d_out, int out_size, void* d_ws, size_t ws_size,
                              hipStream_t stream) {
  const float* q = (const float*)d_in[0];  // (1,32,128,128)
  const float* k = (const float*)d_in[1];  // (1,32,128,128)
  const float* v = (const float*)d_in[2];  // (4,64,128,128)
  float* out = (float*)d_out;

  uint32_t* ws = (uint32_t*)d_ws;
  uint32_t* pk[2] = { ws, ws + (size_t)KNN * NPIX };
  float* ct[2] = { (float*)(ws + (size_t)2 * KNN * NPIX),
                   (float*)(ws + (size_t)3 * KNN * NPIX) };
  float* wbuf = (float*)(ws + (size_t)4 * KNN * NPIX);
  float* ap   = (float*)(ws + (size_t)5 * KNN * NPIX);
  float* bp   = ap + (size_t)32 * PCH;

  // key chain on host (pure arithmetic; graph-capture safe, deterministic)
  uint32_t sp[4];
  h_split_fl(0u, 42u, sp);                      // split(key(42)) [foldlike]
  uint32_t k0a = sp[0], k0b = sp[1];            // k0  (initial randint key)
  uint32_t kMa = sp[2], kMb = sp[3];            // key (closed over by scan body)

  pad_kernel<<<(32 * PCH + 255) / 256, 256, 0, stream>>>(q, k, ap, bp);

  uint32_t ik[4];
  h_split_fl(k0a, k0b, ik);                     // randint's internal split of k0
  init_kernel<<<(KNN * NPIX) / 256, 256, 0, stream>>>(ap, bp, pk[0], ct[0],
                                        make_uint4(ik[0], ik[1], ik[2], ik[3]));

  for (int it = 0; it < 10; ++it) {
    uint32_t ka, kb;
    tf2x32(kMa, kMb, 0u, (uint32_t)it, ka, kb); // kk = fold_in(key, it)
    uint4 K[4];
    for (int i = 0; i < 4; ++i) {
      uint32_t ia, ib;
      tf2x32(ka, kb, 0u, (uint32_t)i, ia, ib);  // ki = fold_in(kk, i)
      uint32_t o[4];
      h_split_fl(ia, ib, o);                    // randint's internal split of ki
      K[i] = make_uint4(o[0], o[1], o[2], o[3]);
    }
    step_kernel<<<4096, 256, 0, stream>>>(ap, bp, pk[it & 1], ct[it & 1],
                                          pk[(it + 1) & 1], ct[(it + 1) & 1],
                                          K[0], K[1], K[2], K[3]);
  }

  weights_kernel<<<NPIX / 256, 256, 0, stream>>>(ct[0], wbuf);
  out_kernel<<<(4 * 64 * NPIX) / 256, 256, 0, stream>>>(v, pk[0], wbuf, out);
}

// Round 4
// 1746.120 us; speedup vs baseline: 2.0003x; 1.1018x over previous
//
#include <hip/hip_runtime.h>
#include <cstdint>

#define NPIX 16384
#define KNN 8
#define PW 130                 // padded width/height
#define NPPAD (PW * PW)        // padded positions: 16900
#define ROWSTRIDE (PW * 32)    // channel-last floats per padded row

typedef float f32x4 __attribute__((ext_vector_type(4)));

// ---------------- Threefry-2x32 (exact JAX semantics: 20 rounds) ----------------
__host__ __device__ __forceinline__ void tf2x32(uint32_t k0, uint32_t k1,
                                                uint32_t x0, uint32_t x1,
                                                uint32_t& o0, uint32_t& o1) {
  uint32_t ks2 = k0 ^ k1 ^ 0x1BD11BDAu;
  x0 += k0; x1 += k1;
#define TFR(r) { x0 += x1; x1 = (x1 << r) | (x1 >> (32 - r)); x1 ^= x0; }
  TFR(13) TFR(15) TFR(26) TFR(6)  x0 += k1;  x1 += ks2 + 1u;
  TFR(17) TFR(29) TFR(16) TFR(24) x0 += ks2; x1 += k0 + 2u;
  TFR(13) TFR(15) TFR(26) TFR(6)  x0 += k0;  x1 += k1 + 3u;
  TFR(17) TFR(29) TFR(16) TFR(24) x0 += k1;  x1 += ks2 + 4u;
  TFR(13) TFR(15) TFR(26) TFR(6)  x0 += ks2; x1 += k0 + 5u;
#undef TFR
  o0 = x0; o1 = x1;
}

// partitionable-threefry random_bits (32-bit): element j -> w0^w1 of TF(key,(0,j))
__device__ __forceinline__ uint32_t rbits32(uint32_t ka, uint32_t kb, uint32_t j) {
  uint32_t o0, o1;
  tf2x32(ka, kb, 0u, j, o0, o1);
  return o0 ^ o1;
}

// randint element draw; K = (k1a,k1b,k2a,k2b) = foldlike-split of randint key
__device__ __forceinline__ int rnd_int(uint4 K, uint32_t j, uint32_t span,
                                       uint32_t mult, int minv) {
  uint32_t hi = rbits32(K.x, K.y, j);
  uint32_t lo = rbits32(K.z, K.w, j);
  uint32_t off = ((hi % span) * mult + (lo % span)) % span;
  return minv + (int)off;
}

// ---------------- patch SSD cost, channel-last padded layout --------------------
// Bit-exact (c, dy, dx) sequential f32 accumulation, no FMA contraction.
// Per 4-channel chunk: load 9 a-quads + 9 b-quads (16B aligned), then accumulate
// j=0..3 (channel order) x 9 positions (dy,dx order) -> global order (c,dy,dx).
__device__ __forceinline__ float cost_eval(const float* __restrict__ apt,
                                           const float* __restrict__ bpt,
                                           int ra, int rb) {
  const float* abase = apt + (size_t)ra * 32;
  const float* bbase = bpt + (size_t)rb * 32;
  float acc = 0.f;
#pragma unroll 2
  for (int cc = 0; cc < 32; cc += 4) {
    f32x4 av[9], bv[9];
#pragma unroll
    for (int dy = 0; dy < 3; ++dy) {
#pragma unroll
      for (int dx = 0; dx < 3; ++dx) {
        av[dy * 3 + dx] = *(const f32x4*)(abase + dy * ROWSTRIDE + dx * 32 + cc);
        bv[dy * 3 + dx] = *(const f32x4*)(bbase + dy * ROWSTRIDE + dx * 32 + cc);
      }
    }
#pragma unroll
    for (int j = 0; j < 4; ++j) {
#pragma unroll
      for (int p = 0; p < 9; ++p) {
        float d = __fsub_rn(av[p][j], bv[p][j]);
        acc = __fadd_rn(acc, __fmul_rn(d, d));
      }
    }
  }
  return acc;
}

// ---------------- pad + transpose a,b to channel-last 130x130 -------------------
__global__ __launch_bounds__(256) void pad_kernel(
    const float* __restrict__ a, const float* __restrict__ b,
    float* __restrict__ apt, float* __restrict__ bpt) {
  int t = (int)(blockIdx.x * blockDim.x + threadIdx.x);
  if (t >= 32 * NPPAD) return;
  int r = t >> 5, c = t & 31;
  int py = r / PW, px = r % PW;
  int y = py - 1; y = y < 0 ? 0 : (y > 127 ? 127 : y);
  int x = px - 1; x = x < 0 ? 0 : (x > 127 ? 127 : x);
  int src = (c << 14) + (y << 7) + x;
  apt[t] = a[src];
  bpt[t] = b[src];
}

// ---------------- init: random shifts + their costs (full-wave) -----------------
__global__ __launch_bounds__(256) void init_kernel(
    const float* __restrict__ apt, const float* __restrict__ bpt,
    uint32_t* __restrict__ npack, float* __restrict__ ncost, uint4 IK) {
  int t = (int)(blockIdx.x * blockDim.x + threadIdx.x);  // 8*16384
  int pix = t & (NPIX - 1);
  int s = t >> 14;
  int h = pix >> 7, w = pix & 127;
  uint32_t j0 = (uint32_t)(s * 2) * 16384u + (uint32_t)pix;
  int sy = rnd_int(IK, j0, 128u, 0u, 0);
  int sx = rnd_int(IK, j0 + 16384u, 128u, 0u, 0);
  float cst = cost_eval(apt, bpt, h * PW + w, sy * PW + sx);
  npack[t] = (uint32_t)((sy << 7) | sx);
  ncost[t] = cst;
}

// ---------------- one PatchMatch iteration (wave per pixel) ---------------------
__global__ __launch_bounds__(256) void step_kernel(
    const float* __restrict__ apt, const float* __restrict__ bpt,
    const uint32_t* __restrict__ ppack, const float* __restrict__ pcost,
    uint32_t* __restrict__ npack, float* __restrict__ ncost,
    uint4 K0, uint4 K1, uint4 K2, uint4 K3) {
  int wid = (int)((blockIdx.x * blockDim.x + threadIdx.x) >> 6);
  int lane = (int)(threadIdx.x & 63u);
  int pix = wid;
  int h = pix >> 7, w = pix & 127;
  int g = lane >> 3, s = lane & 7;

  uint32_t old_pack = 0u; float old_cost_f = 0.f;
  if (lane < 8) {
    old_pack = ppack[lane * NPIX + pix];
    old_cost_f = pcost[lane * NPIX + pix];
  }

  // candidate generation; order matches all_s = [old8, left8, right8, up8, down8, r0..r3]
  int sy, sx;
  if (g < 4) {
    int nh = h, nw = w, dsy = 0, dsx = 0;
    if (g == 0)      { nw = (w + 127) & 127; dsx = 1;  }
    else if (g == 1) { nw = (w + 1) & 127;   dsx = -1; }
    else if (g == 2) { nh = (h + 127) & 127; dsy = 1;  }
    else             { nh = (h + 1) & 127;   dsy = -1; }
    uint32_t p = ppack[s * NPIX + (nh << 7) + nw];
    sy = (int)(p >> 7) + dsy;
    sx = (int)(p & 127u) + dsx;
  } else {
    uint32_t p = ppack[s * NPIX + pix];
    uint4 Ki      = (g == 4) ? K0   : (g == 5) ? K1  : (g == 6) ? K2 : K3;
    uint32_t span = (g == 4) ? 129u : (g == 5) ? 33u : (g == 6) ? 9u : 3u;
    uint32_t mult = (g == 4) ? 16u  : (g == 5) ? 4u  : (g == 6) ? 4u : 1u;
    int minv      = (g == 4) ? -64  : (g == 5) ? -16 : (g == 6) ? -4 : -1;
    uint32_t j0 = (uint32_t)(s * 2) * 16384u + (uint32_t)pix;
    sy = (int)(p >> 7)   + rnd_int(Ki, j0, span, mult, minv);
    sx = (int)(p & 127u) + rnd_int(Ki, j0 + 16384u, span, mult, minv);
  }
  sy = sy < 0 ? 0 : (sy > 127 ? 127 : sy);
  sx = sx < 0 ? 0 : (sx > 127 ? 127 : sx);
  uint32_t cnd_pack = (uint32_t)((sy << 7) | sx);

  // dedup vs the 8 carried shifts: identical shift -> identical (bit-exact) cost
  bool dupOld = false; float dup_cost = 0.f;
#pragma unroll
  for (int i = 0; i < 8; ++i) {
    uint32_t op = __shfl(old_pack, i);
    float oc = __shfl(old_cost_f, i);
    bool m = (op == cnd_pack);
    dupOld = dupOld || m;
    dup_cost = m ? oc : dup_cost;
  }

  // dedup among the 64 new candidates: leader = lowest lane with same pack
  int leader = 64;
#pragma unroll
  for (int i = 0; i < 64; ++i) {
    uint32_t op = __shfl(cnd_pack, i);
    if (op == cnd_pack && i < leader) leader = i;
  }
  bool evalMe = (!dupOld) && (leader == lane);

  float ev = 0.f;
  if (evalMe) ev = cost_eval(apt, bpt, h * PW + w, sy * PW + sx);
  float led = __shfl(ev, leader);   // leader of a non-dupOld lane always evaluated
  float cnd_cost = dupOld ? dup_cost : led;

  // stable top-8 (ascending cost, ties -> lower candidate idx), matching lax.top_k
  unsigned long long new_key =
      ((unsigned long long)__float_as_uint(cnd_cost) << 32) | (unsigned)(8 + lane);
  unsigned long long old_key = (lane < 8)
      ? (((unsigned long long)__float_as_uint(old_cost_f) << 32) | (unsigned)lane)
      : ~0ull;
  bool new_used = false, old_used = (lane >= 8);

  unsigned long long wk0, wk1, wk2, wk3, wk4, wk5, wk6, wk7;
#define SELECT_ROUND(WK)                                                   \
  {                                                                        \
    unsigned long long kmin = new_used ? ~0ull : new_key;                  \
    if (!old_used && old_key < kmin) kmin = old_key;                       \
    _Pragma("unroll")                                                      \
    for (int off = 32; off; off >>= 1) {                                   \
      unsigned long long o = __shfl_xor(kmin, off);                        \
      if (o < kmin) kmin = o;                                              \
    }                                                                      \
    WK = kmin;                                                             \
    if (!new_used && new_key == kmin) new_used = true;                     \
    else if (!old_used && old_key == kmin) old_used = true;                \
  }
  SELECT_ROUND(wk0) SELECT_ROUND(wk1) SELECT_ROUND(wk2) SELECT_ROUND(wk3)
  SELECT_ROUND(wk4) SELECT_ROUND(wk5) SELECT_ROUND(wk6) SELECT_ROUND(wk7)
#undef SELECT_ROUND

  uint32_t out_pack = 0u; float out_cost = 0.f;
#define EXTRACT_ROUND(R, WK)                                               \
  {                                                                        \
    unsigned long long kmin = WK;                                          \
    uint32_t idx = (uint32_t)kmin;                                         \
    float cst = __uint_as_float((uint32_t)(kmin >> 32));                   \
    int srcOld = (idx < 8u) ? (int)idx : 0;                                \
    int srcNew = (idx >= 8u) ? (int)(idx - 8u) : 0;                        \
    uint32_t po = __shfl(old_pack, srcOld);                                \
    uint32_t pn = __shfl(cnd_pack, srcNew);                                \
    uint32_t pk = (idx < 8u) ? po : pn;                                    \
    if (lane == R) { out_pack = pk; out_cost = cst; }                      \
  }
  EXTRACT_ROUND(0, wk0) EXTRACT_ROUND(1, wk1) EXTRACT_ROUND(2, wk2)
  EXTRACT_ROUND(3, wk3) EXTRACT_ROUND(4, wk4) EXTRACT_ROUND(5, wk5)
  EXTRACT_ROUND(6, wk6) EXTRACT_ROUND(7, wk7)
#undef EXTRACT_ROUND

  if (lane < 8) {
    npack[lane * NPIX + pix] = out_pack;
    ncost[lane * NPIX + pix] = out_cost;
  }
}

// ---------------- softmax weights over 8 costs ----------------------------------
__global__ __launch_bounds__(256) void weights_kernel(
    const float* __restrict__ cost0, float* __restrict__ wbuf) {
  int pix = (int)(blockIdx.x * blockDim.x + threadIdx.x);
  if (pix >= NPIX) return;
  float c[KNN];
  float m = 3.4e38f;
#pragma unroll
  for (int s = 0; s < KNN; ++s) { c[s] = cost0[s * NPIX + pix]; m = fminf(m, c[s]); }
  float e[KNN]; float sum = 0.f;
#pragma unroll
  for (int s = 0; s < KNN; ++s) { e[s] = expf(m - c[s]); sum += e[s]; }
  float inv = 1.f / sum;
#pragma unroll
  for (int s = 0; s < KNN; ++s) wbuf[s * NPIX + pix] = e[s] * inv;
}

// ---------------- weighted gather of v ------------------------------------------
__global__ __launch_bounds__(256) void out_kernel(
    const float* __restrict__ v, const uint32_t* __restrict__ pack0,
    const float* __restrict__ wbuf, float* __restrict__ out) {
  int t = (int)(blockIdx.x * blockDim.x + threadIdx.x);  // 4*64*128*128 threads
  int pix = t & (NPIX - 1);
  int ch = t >> 14;  // n*64 + c2
  const float* vc = v + ((size_t)ch << 14);
  float acc = 0.f;
#pragma unroll
  for (int s = 0; s < KNN; ++s) {
    uint32_t p = pack0[s * NPIX + pix];   // p == sy*128+sx
    float wgt = wbuf[s * NPIX + pix];
    acc = fmaf(wgt, vc[p], acc);
  }
  out[t] = acc;
}

// ---------------- host helpers ---------------------------------------------------
// foldlike split (jax_threefry_partitionable=True): key_i = TF(key, (0, i))
static void h_split_fl(uint32_t ka, uint32_t kb, uint32_t o[4]) {
  tf2x32(ka, kb, 0u, 0u, o[0], o[1]);  // keys[0]
  tf2x32(ka, kb, 0u, 1u, o[2], o[3]);  // keys[1]
}

extern "C" void kernel_launch(void* const* d_in, const int* in_sizes, int n_in,
                              void* d_out, int out_size, void* d_ws, size_t ws_size,
                              hipStream_t stream) {
  const float* q = (const float*)d_in[0];  // (1,32,128,128)
  const float* k = (const float*)d_in[1];  // (1,32,128,128)
  const float* v = (const float*)d_in[2];  // (4,64,128,128)
  float* out = (float*)d_out;

  uint32_t* ws = (uint32_t*)d_ws;
  uint32_t* pk[2] = { ws, ws + (size_t)KNN * NPIX };
  float* ct[2] = { (float*)(ws + (size_t)2 * KNN * NPIX),
                   (float*)(ws + (size_t)3 * KNN * NPIX) };
  float* wbuf = (float*)(ws + (size_t)4 * KNN * NPIX);
  float* apt  = (float*)(ws + (size_t)5 * KNN * NPIX);
  float* bpt  = apt + (size_t)32 * NPPAD;

  // key chain on host (pure arithmetic; graph-capture safe, deterministic)
  uint32_t sp[4];
  h_split_fl(0u, 42u, sp);                      // split(key(42)) [foldlike]
  uint32_t k0a = sp[0], k0b = sp[1];            // k0  (initial randint key)
  uint32_t kMa = sp[2], kMb = sp[3];            // key (closed over by scan body)

  pad_kernel<<<(32 * NPPAD + 255) / 256, 256, 0, stream>>>(q, k, apt, bpt);

  uint32_t ik[4];
  h_split_fl(k0a, k0b, ik);                     // randint's internal split of k0
  init_kernel<<<(KNN * NPIX) / 256, 256, 0, stream>>>(apt, bpt, pk[0], ct[0],
                                        make_uint4(ik[0], ik[1], ik[2], ik[3]));

  for (int it = 0; it < 10; ++it) {
    uint32_t ka, kb;
    tf2x32(kMa, kMb, 0u, (uint32_t)it, ka, kb); // kk = fold_in(key, it)
    uint4 K[4];
    for (int i = 0; i < 4; ++i) {
      uint32_t ia, ib;
      tf2x32(ka, kb, 0u, (uint32_t)i, ia, ib);  // ki = fold_in(kk, i)
      uint32_t o[4];
      h_split_fl(ia, ib, o);                    // randint's internal split of ki
      K[i] = make_uint4(o[0], o[1], o[2], o[3]);
    }
    step_kernel<<<4096, 256, 0, stream>>>(apt, bpt, pk[it & 1], ct[it & 1],
                                          pk[(it + 1) & 1], ct[(it + 1) & 1],
                                          K[0], K[1], K[2], K[3]);
  }

  weights_kernel<<<NPIX / 256, 256, 0, stream>>>(ct[0], wbuf);
  out_kernel<<<(4 * 64 * NPIX) / 256, 256, 0, stream>>>(v, pk[0], wbuf, out);
}